// Round 1
// baseline (15466.814 us; speedup 1.0000x reference)
//
#include <hip/hip_runtime.h>

// CV quantum neural network simulator, D=8 cutoff, M=4 modes, L=4 layers.
// State per sample: 4096 complex64 = 32 KB -> LDS-resident, 1 block/sample.

#define DC 8          // cutoff
#define NM 4          // modes
#define NL 4          // layers
#define AMPS 4096     // DC^NM

__device__ __forceinline__ void cmac(float2& acc, float2 a, float2 b) {
    acc.x = fmaf(a.x, b.x, acc.x);
    acc.x = fmaf(-a.y, b.y, acc.x);
    acc.y = fmaf(a.x, b.y, acc.y);
    acc.y = fmaf(a.y, b.x, acc.y);
}

// ---------------------------------------------------------------------------
// Kernel 1: coherent vectors c[b][m][0..7] = first column of expm(x*(AD - A)).
// K = AD - A is real antisymmetric tridiagonal: (Kv)[i] = sq[i]*v[i-1] - sq[i+1]*v[i+1].
// exp(alpha*K) e0 via 32 substeps of order-8 vector Taylor (exact same matrix
// function as the reference's expm, error ~1e-10).
// ---------------------------------------------------------------------------
__global__ void coh_kernel(const float* __restrict__ x, float* __restrict__ coh, int total) {
    int t = blockIdx.x * blockDim.x + threadIdx.x;
    if (t >= total) return;
    float alpha = x[t];
    const float sq1 = 1.0f, sq2 = 1.41421356f, sq3 = 1.73205081f, sq4 = 2.0f,
                sq5 = 2.23606798f, sq6 = 2.44948975f, sq7 = 2.64575131f;
    float v0 = 1.f, v1 = 0.f, v2 = 0.f, v3 = 0.f, v4 = 0.f, v5 = 0.f, v6 = 0.f, v7 = 0.f;
    const int NS = 32;
    float h = alpha / (float)NS;
    for (int s = 0; s < NS; s++) {
        float w0 = v0, w1 = v1, w2 = v2, w3 = v3, w4 = v4, w5 = v5, w6 = v6, w7 = v7;
        float t0 = v0, t1 = v1, t2 = v2, t3 = v3, t4 = v4, t5 = v5, t6 = v6, t7 = v7;
        #pragma unroll
        for (int j = 1; j <= 8; j++) {
            float c = h / (float)j;
            float n0 = c * (          - sq1 * t1);
            float n1 = c * (sq1 * t0 - sq2 * t2);
            float n2 = c * (sq2 * t1 - sq3 * t3);
            float n3 = c * (sq3 * t2 - sq4 * t4);
            float n4 = c * (sq4 * t3 - sq5 * t5);
            float n5 = c * (sq5 * t4 - sq6 * t6);
            float n6 = c * (sq6 * t5 - sq7 * t7);
            float n7 = c * (sq7 * t6            );
            t0 = n0; t1 = n1; t2 = n2; t3 = n3; t4 = n4; t5 = n5; t6 = n6; t7 = n7;
            w0 += t0; w1 += t1; w2 += t2; w3 += t3; w4 += t4; w5 += t5; w6 += t6; w7 += t7;
        }
        v0 = w0; v1 = w1; v2 = w2; v3 = w3; v4 = w4; v5 = w5; v6 = w6; v7 = w7;
    }
    float* dst = coh + t * 8;
    dst[0] = v0; dst[1] = v1; dst[2] = v2; dst[3] = v3;
    dst[4] = v4; dst[5] = v5; dst[6] = v6; dst[7] = v7;
}

// ---------------------------------------------------------------------------
// Kernel 2: 8x8 complex expm for squeeze (blocks 0..15) and in-layer
// displacement (blocks 16..31). One block = 64 threads, thread t owns (r,c).
// Scaling-and-squaring + order-9 Horner Taylor.
// ---------------------------------------------------------------------------
__global__ __launch_bounds__(64) void expm8_kernel(
    const float* __restrict__ sqr, const float* __restrict__ sqph,
    const float* __restrict__ dpr, const float* __restrict__ dpph,
    float2* __restrict__ sqm, float2* __restrict__ dpm) {
    __shared__ float2 X[64], R[64];
    int t = threadIdx.x;
    int r = t >> 3, c = t & 7;
    int bid = blockIdx.x;
    float2 h = make_float2(0.f, 0.f);
    float normb;
    if (bid < 16) {
        // S(z) = exp(0.5*(conj(z) A^2 - z AD^2)), z = r e^{i phi}
        float rr = sqr[bid], ph = sqph[bid];
        float zr = rr * cosf(ph), zi = rr * sinf(ph);
        if (c == r + 2) { float f = 0.5f * sqrtf((float)((r + 1) * (r + 2))); h.x =  f * zr; h.y = -f * zi; }
        if (r == c + 2) { float f = 0.5f * sqrtf((float)((c + 1) * (c + 2))); h.x = -f * zr; h.y = -f * zi; }
        normb = fabsf(rr) * 5.5f;
    } else {
        // D(alpha), alpha = (r cos ph) * exp(i * r sin ph); H = alpha AD - conj(alpha) A
        int g = bid - 16;
        float rr = dpr[g], ph = dpph[g];
        float am = rr * cosf(ph);
        float aph = rr * sinf(ph);
        float ar = am * cosf(aph), ai = am * sinf(aph);
        if (r == c + 1) { float f = sqrtf((float)r); h.x += ar * f; h.y += ai * f; }
        if (c == r + 1) { float f = sqrtf((float)c); h.x -= ar * f; h.y += ai * f; }
        normb = fabsf(am) * 5.5f;
    }
    int s = 0;
    while (normb > 0.2f && s < 20) { normb *= 0.5f; s++; }
    float fs = 1.f;
    for (int q = 0; q < s; q++) fs *= 0.5f;
    float2 xs = make_float2(h.x * fs, h.y * fs);
    X[t] = xs;
    float idel = (r == c) ? 1.f : 0.f;
    R[t] = make_float2(idel + xs.x / 9.f, xs.y / 9.f);
    __syncthreads();
    for (int j = 8; j >= 1; j--) {
        float2 acc = make_float2(0.f, 0.f);
        #pragma unroll
        for (int k = 0; k < 8; k++) cmac(acc, X[r * 8 + k], R[k * 8 + c]);
        __syncthreads();
        float inv = 1.f / (float)j;
        R[t] = make_float2(idel + acc.x * inv, acc.y * inv);
        __syncthreads();
    }
    for (int q = 0; q < s; q++) {
        float2 acc = make_float2(0.f, 0.f);
        #pragma unroll
        for (int k = 0; k < 8; k++) cmac(acc, R[r * 8 + k], R[k * 8 + c]);
        __syncthreads();
        R[t] = acc;
        __syncthreads();
    }
    float2* dst = (bid < 16) ? (sqm + bid * 64) : (dpm + (bid - 16) * 64);
    dst[t] = R[t];  // row-major U[i*8+k]
}

// ---------------------------------------------------------------------------
// Kernel 3: 64x64 complex expm for the 48 beamsplitters.
// blk = l*12 + idx; idx<6 -> (theta_1,phi_1) pair idx, else (theta_2,phi_2).
// H[(a,b),(a+1,b-1)] = t e^{ip} sqrt((a+1)b); H[(a,b),(a-1,b+1)] = -t e^{-ip} sqrt(a(b+1)).
// Stored TRANSPOSED (bsm[blk][col*64+row]) for conflict-free LDS reads downstream.
// ---------------------------------------------------------------------------
__global__ __launch_bounds__(256) void expm64_kernel(
    const float* __restrict__ th1, const float* __restrict__ ph1,
    const float* __restrict__ th2, const float* __restrict__ ph2,
    float2* __restrict__ bsm) {
    __shared__ float2 X[4096], R[4096];
    int blk = blockIdx.x;
    int l = blk / 12, idx = blk % 12;
    int p = (idx < 6) ? idx : idx - 6;
    int mi = (p < 3) ? 0 : ((p < 5) ? 1 : 2);
    int mj = (p == 0) ? 1 : ((p == 1 || p == 3) ? 2 : 3);
    const float* th = (idx < 6) ? th1 : th2;
    const float* ph = (idx < 6) ? ph1 : ph2;
    float tt = th[l * 16 + mi * 4 + mj];
    float pp = ph[l * 16 + mi * 4 + mj];
    float cp = cosf(pp), sp = sinf(pp);
    int t = threadIdx.x;
    float normb = fabsf(tt) * 13.94f;
    int s = 0;
    while (normb > 0.2f && s < 20) { normb *= 0.5f; s++; }
    float fs = 1.f;
    for (int q = 0; q < s; q++) fs *= 0.5f;
    for (int e = t; e < 4096; e += 256) {
        int r = e >> 6, c = e & 63;
        int a = r >> 3, b = r & 7, ca = c >> 3, cb = c & 7;
        float2 h = make_float2(0.f, 0.f);
        if (ca == a + 1 && cb == b - 1) {
            float g = tt * sqrtf((float)((a + 1) * b));
            h.x = g * cp; h.y = g * sp;
        } else if (ca == a - 1 && cb == b + 1) {
            float g = tt * sqrtf((float)(a * (b + 1)));
            h.x = -g * cp; h.y = g * sp;
        }
        float2 xs = make_float2(h.x * fs, h.y * fs);
        X[e] = xs;
        R[e] = make_float2(((r == c) ? 1.f : 0.f) + xs.x * 0.1f, xs.y * 0.1f);  // I + X/10
    }
    __syncthreads();
    float2 acc[16];
    for (int j = 9; j >= 1; j--) {
        int q = 0;
        for (int e = t; e < 4096; e += 256, q++) {
            int r = e >> 6, c = e & 63;
            float2 a2 = make_float2(0.f, 0.f);
            for (int k = 0; k < 64; k++) cmac(a2, X[r * 64 + k], R[k * 64 + c]);
            acc[q] = a2;
        }
        __syncthreads();
        float inv = 1.f / (float)j;
        q = 0;
        for (int e = t; e < 4096; e += 256, q++) {
            int r = e >> 6, c = e & 63;
            R[e] = make_float2(((r == c) ? 1.f : 0.f) + acc[q].x * inv, acc[q].y * inv);
        }
        __syncthreads();
    }
    for (int sq = 0; sq < s; sq++) {
        int q = 0;
        for (int e = t; e < 4096; e += 256, q++) {
            int r = e >> 6, c = e & 63;
            float2 a2 = make_float2(0.f, 0.f);
            for (int k = 0; k < 64; k++) cmac(a2, R[r * 64 + k], R[k * 64 + c]);
            acc[q] = a2;
        }
        __syncthreads();
        q = 0;
        for (int e = t; e < 4096; e += 256, q++) R[e] = acc[q];
        __syncthreads();
    }
    for (int e = t; e < 4096; e += 256) {
        int r = e >> 6, c = e & 63;
        bsm[blk * 4096 + c * 64 + r] = R[e];  // transposed
    }
}

// ---------------------------------------------------------------------------
// Main simulation kernel. One block (256 thr) per sample; state in LDS.
// ---------------------------------------------------------------------------
__device__ __forceinline__ void apply_diag_rot(float2* S, float phv, int m, int t) {
    int sh = 3 * (3 - m);
    for (int e = t; e < AMPS; e += 256) {
        int n = (e >> sh) & 7;
        float sn, cn;
        sincosf(phv * (float)n, &sn, &cn);
        float2 sv = S[e];
        S[e] = make_float2(sv.x * cn - sv.y * sn, sv.x * sn + sv.y * cn);
    }
}

__device__ __forceinline__ void apply_diag_kerr(float2* S, float kp, int m, int t) {
    int sh = 3 * (3 - m);
    for (int e = t; e < AMPS; e += 256) {
        int n = (e >> sh) & 7;
        float sn, cn;
        sincosf(kp * (float)(n * n), &sn, &cn);
        float2 sv = S[e];
        S[e] = make_float2(sv.x * cn - sv.y * sn, sv.x * sn + sv.y * cn);
    }
}

// Single-mode 8x8 gate; U8 (row-major) staged into G[0..63].
__device__ void apply1(float2* S, float2* G, const float2* __restrict__ U8, int m, int t) {
    if (t < 64) G[t] = U8[t];
    __syncthreads();
    int st = 512 >> (3 * m);
    for (int f = t; f < 512; f += 256) {
        int base = 0, tmp = f;
        #pragma unroll
        for (int mm = 3; mm >= 0; mm--) {
            if (mm != m) { base += (tmp & 7) * (512 >> (3 * mm)); tmp >>= 3; }
        }
        float2 v[8];
        #pragma unroll
        for (int k = 0; k < 8; k++) v[k] = S[base + k * st];
        #pragma unroll
        for (int i = 0; i < 8; i++) {
            float2 a2 = make_float2(0.f, 0.f);
            #pragma unroll
            for (int k = 0; k < 8; k++) cmac(a2, G[i * 8 + k], v[k]);
            S[base + i * st] = a2;
        }
    }
    __syncthreads();
}

// Two-mode 64x64 gate, G holds transposed gate GT[k*64 + out]. Lane = out index,
// each wave owns 16 outer fibers (in-place safe: all reads precede writes in
// the wave's program order; fibers are wave-private).
template<int M1, int M2>
__device__ __attribute__((noinline)) void apply2t(float2* S, const float2* G, int lane, int wave) {
    constexpr int st1 = 512 >> (3 * M1);
    constexpr int st2 = 512 >> (3 * M2);
    int sa = 0, sb = 0, q = 0;
    #pragma unroll
    for (int mm = 0; mm < 4; mm++) {
        if (mm != M1 && mm != M2) {
            if (q == 0) sa = 512 >> (3 * mm); else sb = 512 >> (3 * mm);
            q++;
        }
    }
    int bases[16];
    #pragma unroll
    for (int j = 0; j < 16; j++) {
        int oo = wave + 4 * j;
        bases[j] = (oo >> 3) * sa + (oo & 7) * sb;
    }
    float2 acc[16];
    #pragma unroll
    for (int j = 0; j < 16; j++) acc[j] = make_float2(0.f, 0.f);
    #pragma unroll 1
    for (int ka = 0; ka < 8; ka++) {
        int koff = ka * st1;
        int ubase = ka * 512 + lane;
        #pragma unroll 4
        for (int kb = 0; kb < 8; kb++) {
            float2 u = G[ubase + kb * 64];
            int ko = koff + kb * st2;
            #pragma unroll
            for (int j = 0; j < 16; j++) {
                float2 sv = S[bases[j] + ko];   // broadcast read
                cmac(acc[j], u, sv);
            }
        }
    }
    int outoff = (lane >> 3) * st1 + (lane & 7) * st2;
    #pragma unroll
    for (int j = 0; j < 16; j++) S[bases[j] + outoff] = acc[j];
}

__device__ void do_bs(float2* S, float2* G, const float2* __restrict__ UT, int p,
                      int t, int lane, int wave) {
    for (int e = t; e < AMPS; e += 256) G[e] = UT[e];
    __syncthreads();
    switch (p) {
        case 0: apply2t<0, 1>(S, G, lane, wave); break;
        case 1: apply2t<0, 2>(S, G, lane, wave); break;
        case 2: apply2t<0, 3>(S, G, lane, wave); break;
        case 3: apply2t<1, 2>(S, G, lane, wave); break;
        case 4: apply2t<1, 3>(S, G, lane, wave); break;
        default: apply2t<2, 3>(S, G, lane, wave); break;
    }
    __syncthreads();
}

__device__ void interferometer(float2* S, float2* G, const float2* __restrict__ bs,
                               const float* __restrict__ phim, int t, int lane, int wave) {
    #pragma unroll 1
    for (int i = 0; i < 4; i++) apply_diag_rot(S, phim[i * 4 + i], i, t);
    int p = 0;
    #pragma unroll 1
    for (int i = 0; i < 4; i++) {
        #pragma unroll 1
        for (int j = i + 1; j < 4; j++) {
            do_bs(S, G, bs + p * 4096, p, t, lane, wave);
            apply_diag_rot(S, phim[j * 4 + i], j, t);
            p++;
        }
    }
}

__global__ __launch_bounds__(256) void sim_kernel(
    const float* __restrict__ coh, const float2* __restrict__ sqm,
    const float2* __restrict__ dpm, const float2* __restrict__ bsm,
    const float* __restrict__ ph1, const float* __restrict__ ph2,
    const float* __restrict__ kerr, float* __restrict__ out) {
    __shared__ float2 S[AMPS];
    __shared__ float2 G[AMPS];
    int b = blockIdx.x;
    int t = threadIdx.x;
    int lane = t & 63, wave = t >> 6;

    // Initial product state from the 4 coherent vectors (all real).
    float* Gf = (float*)G;
    if (t < 32) Gf[t] = coh[b * 32 + t];
    __syncthreads();
    for (int e = t; e < AMPS; e += 256) {
        float v = Gf[e >> 9] * Gf[8 + ((e >> 6) & 7)] * Gf[16 + ((e >> 3) & 7)] * Gf[24 + (e & 7)];
        S[e] = make_float2(v, 0.f);
    }
    __syncthreads();

    #pragma unroll 1
    for (int l = 0; l < NL; l++) {
        interferometer(S, G, bsm + (l * 12) * 4096, ph1 + l * 16, t, lane, wave);
        #pragma unroll 1
        for (int w = 0; w < 4; w++) apply1(S, G, sqm + (l * 4 + w) * 64, w, t);
        interferometer(S, G, bsm + (l * 12 + 6) * 4096, ph2 + l * 16, t, lane, wave);
        #pragma unroll 1
        for (int w = 0; w < 4; w++) apply1(S, G, dpm + (l * 4 + w) * 64, w, t);
        #pragma unroll 1
        for (int w = 0; w < 4; w++) apply_diag_kerr(S, kerr[l * 4 + w], w, t);
    }

    // <n_w> per mode.
    float ev0 = 0.f, ev1 = 0.f, ev2 = 0.f, ev3 = 0.f;
    for (int e = t; e < AMPS; e += 256) {
        float2 s = S[e];
        float pr = s.x * s.x + s.y * s.y;
        ev0 += pr * (float)(e >> 9);
        ev1 += pr * (float)((e >> 6) & 7);
        ev2 += pr * (float)((e >> 3) & 7);
        ev3 += pr * (float)(e & 7);
    }
    #pragma unroll
    for (int off = 32; off > 0; off >>= 1) {
        ev0 += __shfl_down(ev0, off);
        ev1 += __shfl_down(ev1, off);
        ev2 += __shfl_down(ev2, off);
        ev3 += __shfl_down(ev3, off);
    }
    __syncthreads();
    float* red = (float*)G;
    if (lane == 0) {
        red[wave * 4 + 0] = ev0;
        red[wave * 4 + 1] = ev1;
        red[wave * 4 + 2] = ev2;
        red[wave * 4 + 3] = ev3;
    }
    __syncthreads();
    if (t < 4) out[b * 4 + t] = red[t] + red[4 + t] + red[8 + t] + red[12 + t];
}

extern "C" void kernel_launch(void* const* d_in, const int* in_sizes, int n_in,
                              void* d_out, int out_size, void* d_ws, size_t ws_size,
                              hipStream_t stream) {
    const float* x    = (const float*)d_in[0];
    const float* th1  = (const float*)d_in[1];
    const float* ph1  = (const float*)d_in[2];
    const float* th2  = (const float*)d_in[3];
    const float* ph2  = (const float*)d_in[4];
    const float* dpr  = (const float*)d_in[5];
    const float* dpph = (const float*)d_in[6];
    const float* sqr  = (const float*)d_in[7];
    const float* sqph = (const float*)d_in[8];
    const float* kerr = (const float*)d_in[9];
    float* out = (float*)d_out;

    int Bn = in_sizes[0] / NM;

    char* ws = (char*)d_ws;
    float*  coh = (float*)ws;                          // Bn*4*8 floats
    size_t coh_bytes = (size_t)Bn * 32 * sizeof(float);
    float2* sqm = (float2*)(ws + coh_bytes);           // 16*64 float2
    float2* dpm = (float2*)(ws + coh_bytes + 16 * 64 * sizeof(float2));
    float2* bsm = (float2*)(ws + coh_bytes + 32 * 64 * sizeof(float2)); // 48*4096 float2

    int total = Bn * NM;
    coh_kernel<<<(total + 255) / 256, 256, 0, stream>>>(x, coh, total);
    expm8_kernel<<<32, 64, 0, stream>>>(sqr, sqph, dpr, dpph, sqm, dpm);
    expm64_kernel<<<48, 256, 0, stream>>>(th1, ph1, th2, ph2, bsm);
    sim_kernel<<<Bn, 256, 0, stream>>>(coh, sqm, dpm, bsm, ph1, ph2, kerr, out);
}

// Round 2
// 12388.632 us; speedup vs baseline: 1.2485x; 1.2485x over previous
//
#include <hip/hip_runtime.h>

// CV quantum neural network simulator, D=8 cutoff, M=4 modes, L=4 layers.
// R2: lane=fiber mapping (64 LDS reads/wave/gate instead of 1024 broadcasts),
// scalar-load G from global (no LDS staging), XOR-swizzled state layout
// (kills bank conflicts), all diagonal gates folded into BS / displacement
// matrices at prep time.

#define NM 4
#define NL 4
#define AMPS 4096

__device__ __forceinline__ void cmac(float2& acc, float2 a, float2 b) {
    acc.x = fmaf(a.x, b.x, acc.x);
    acc.x = fmaf(-a.y, b.y, acc.x);
    acc.y = fmaf(a.x, b.y, acc.y);
    acc.y = fmaf(a.y, b.x, acc.y);
}
__device__ __forceinline__ float2 cmul(float2 a, float2 b) {
    return make_float2(a.x * b.x - a.y * b.y, a.x * b.y + a.y * b.x);
}

// F2-linear LDS swizzle: spreads strides 64/512 across banks; involution.
__device__ __forceinline__ constexpr int swz(int e) {
    return (((e >> 6) ^ (e >> 9)) & 7) ^ (((e >> 9) & 1) << 3);
}
__device__ __forceinline__ constexpr int pidx(int e) { return e ^ swz(e); }

// ---------------------------------------------------------------------------
// Kernel 1: coherent vectors c[b][m][0..7] = first column of expm(x*(AD - A)).
// ---------------------------------------------------------------------------
__global__ void coh_kernel(const float* __restrict__ x, float* __restrict__ coh, int total) {
    int t = blockIdx.x * blockDim.x + threadIdx.x;
    if (t >= total) return;
    float alpha = x[t];
    const float sq1 = 1.0f, sq2 = 1.41421356f, sq3 = 1.73205081f, sq4 = 2.0f,
                sq5 = 2.23606798f, sq6 = 2.44948975f, sq7 = 2.64575131f;
    float v0 = 1.f, v1 = 0.f, v2 = 0.f, v3 = 0.f, v4 = 0.f, v5 = 0.f, v6 = 0.f, v7 = 0.f;
    const int NS = 32;
    float h = alpha / (float)NS;
    for (int s = 0; s < NS; s++) {
        float w0 = v0, w1 = v1, w2 = v2, w3 = v3, w4 = v4, w5 = v5, w6 = v6, w7 = v7;
        float t0 = v0, t1 = v1, t2 = v2, t3 = v3, t4 = v4, t5 = v5, t6 = v6, t7 = v7;
        #pragma unroll
        for (int j = 1; j <= 8; j++) {
            float c = h / (float)j;
            float n0 = c * (          - sq1 * t1);
            float n1 = c * (sq1 * t0 - sq2 * t2);
            float n2 = c * (sq2 * t1 - sq3 * t3);
            float n3 = c * (sq3 * t2 - sq4 * t4);
            float n4 = c * (sq4 * t3 - sq5 * t5);
            float n5 = c * (sq5 * t4 - sq6 * t6);
            float n6 = c * (sq6 * t5 - sq7 * t7);
            float n7 = c * (sq7 * t6            );
            t0 = n0; t1 = n1; t2 = n2; t3 = n3; t4 = n4; t5 = n5; t6 = n6; t7 = n7;
            w0 += t0; w1 += t1; w2 += t2; w3 += t3; w4 += t4; w5 += t5; w6 += t6; w7 += t7;
        }
        v0 = w0; v1 = w1; v2 = w2; v3 = w3; v4 = w4; v5 = w5; v6 = w6; v7 = w7;
    }
    float* dst = coh + t * 8;
    dst[0] = v0; dst[1] = v1; dst[2] = v2; dst[3] = v3;
    dst[4] = v4; dst[5] = v5; dst[6] = v6; dst[7] = v7;
}

// ---------------------------------------------------------------------------
// Kernel 2: 8x8 complex expm. Blocks 0..15: squeeze. Blocks 16..31: in-layer
// displacement WITH Kerr diag folded in (left-multiply).
// Output stored TRANSPOSED: dst[k*8 + i] = U[i][k]  (column per k for s_load).
// ---------------------------------------------------------------------------
__global__ __launch_bounds__(64) void expm8_kernel(
    const float* __restrict__ sqr, const float* __restrict__ sqph,
    const float* __restrict__ dpr, const float* __restrict__ dpph,
    const float* __restrict__ kerr,
    float2* __restrict__ sqm, float2* __restrict__ dpm) {
    __shared__ float2 X[64], R[64];
    int t = threadIdx.x;
    int r = t >> 3, c = t & 7;
    int bid = blockIdx.x;
    float2 h = make_float2(0.f, 0.f);
    float normb;
    if (bid < 16) {
        float rr = sqr[bid], ph = sqph[bid];
        float zr = rr * cosf(ph), zi = rr * sinf(ph);
        if (c == r + 2) { float f = 0.5f * sqrtf((float)((r + 1) * (r + 2))); h.x =  f * zr; h.y = -f * zi; }
        if (r == c + 2) { float f = 0.5f * sqrtf((float)((c + 1) * (c + 2))); h.x = -f * zr; h.y = -f * zi; }
        normb = fabsf(rr) * 5.5f;
    } else {
        int g = bid - 16;
        float rr = dpr[g], ph = dpph[g];
        float am = rr * cosf(ph);
        float aph = rr * sinf(ph);
        float ar = am * cosf(aph), ai = am * sinf(aph);
        if (r == c + 1) { float f = sqrtf((float)r); h.x += ar * f; h.y += ai * f; }
        if (c == r + 1) { float f = sqrtf((float)c); h.x -= ar * f; h.y += ai * f; }
        normb = fabsf(am) * 5.5f;
    }
    int s = 0;
    while (normb > 0.2f && s < 20) { normb *= 0.5f; s++; }
    float fs = 1.f;
    for (int q = 0; q < s; q++) fs *= 0.5f;
    float2 xs = make_float2(h.x * fs, h.y * fs);
    X[t] = xs;
    float idel = (r == c) ? 1.f : 0.f;
    R[t] = make_float2(idel + xs.x / 9.f, xs.y / 9.f);
    __syncthreads();
    for (int j = 8; j >= 1; j--) {
        float2 acc = make_float2(0.f, 0.f);
        #pragma unroll
        for (int k = 0; k < 8; k++) cmac(acc, X[r * 8 + k], R[k * 8 + c]);
        __syncthreads();
        float inv = 1.f / (float)j;
        R[t] = make_float2(idel + acc.x * inv, acc.y * inv);
        __syncthreads();
    }
    for (int q = 0; q < s; q++) {
        float2 acc = make_float2(0.f, 0.f);
        #pragma unroll
        for (int k = 0; k < 8; k++) cmac(acc, R[r * 8 + k], R[k * 8 + c]);
        __syncthreads();
        R[t] = acc;
        __syncthreads();
    }
    float2 v = R[t];
    if (bid >= 16) {
        // Kerr(kappa) = diag(e^{i k n^2}) applied AFTER displacement -> scale row r
        float kp = kerr[bid - 16];
        float ang = kp * (float)(r * r);
        float sn, cs; __sincosf(ang, &sn, &cs);
        v = cmul(make_float2(cs, sn), v);
        dpm[(bid - 16) * 64 + c * 8 + r] = v;   // transposed
    } else {
        sqm[bid * 64 + c * 8 + r] = v;          // transposed
    }
}

// ---------------------------------------------------------------------------
// Kernel 3: 64x64 complex expm for the 48 beamsplitters, with interferometer
// diagonal rotations folded in:
//   pre-rots R(phi[i][i]) (start of interferometer) -> column scaling on the
//   first BS touching each mode: p=0 gets phi00,phi11; p=1 gets phi22; p=2 phi33.
//   post-rot R(phi[j][i]) on mode j after BS(i,j) -> row scaling.
// Stored TRANSPOSED: bsm[blk][k*64 + o] = U'[o][k].
// ---------------------------------------------------------------------------
__global__ __launch_bounds__(256) void expm64_kernel(
    const float* __restrict__ th1, const float* __restrict__ ph1,
    const float* __restrict__ th2, const float* __restrict__ ph2,
    float2* __restrict__ bsm) {
    __shared__ float2 X[4096], R[4096];
    int blk = blockIdx.x;
    int l = blk / 12, idx = blk % 12;
    int p = (idx < 6) ? idx : idx - 6;
    int mi = (p < 3) ? 0 : ((p < 5) ? 1 : 2);
    int mj = (p == 0) ? 1 : ((p == 1 || p == 3) ? 2 : 3);
    const float* th = (idx < 6) ? th1 : th2;
    const float* ph = (idx < 6) ? ph1 : ph2;
    float tt = th[l * 16 + mi * 4 + mj];
    float pp = ph[l * 16 + mi * 4 + mj];
    float cp = cosf(pp), sp = sinf(pp);
    float php = ph[l * 16 + mj * 4 + mi];     // post-rot angle on mode mj
    float pre_i = 0.f, pre_j = 0.f;           // pre-rot angles folded on columns
    if (p == 0) { pre_i = ph[l * 16 + 0]; pre_j = ph[l * 16 + 5]; }
    else if (p == 1) { pre_j = ph[l * 16 + 10]; }
    else if (p == 2) { pre_j = ph[l * 16 + 15]; }
    int t = threadIdx.x;
    float normb = fabsf(tt) * 13.94f;
    int s = 0;
    while (normb > 0.2f && s < 20) { normb *= 0.5f; s++; }
    float fs = 1.f;
    for (int q = 0; q < s; q++) fs *= 0.5f;
    for (int e = t; e < 4096; e += 256) {
        int r = e >> 6, c = e & 63;
        int a = r >> 3, b = r & 7, ca = c >> 3, cb = c & 7;
        float2 h = make_float2(0.f, 0.f);
        if (ca == a + 1 && cb == b - 1) {
            float g = tt * sqrtf((float)((a + 1) * b));
            h.x = g * cp; h.y = g * sp;
        } else if (ca == a - 1 && cb == b + 1) {
            float g = tt * sqrtf((float)(a * (b + 1)));
            h.x = -g * cp; h.y = g * sp;
        }
        float2 xs = make_float2(h.x * fs, h.y * fs);
        X[e] = xs;
        R[e] = make_float2(((r == c) ? 1.f : 0.f) + xs.x * 0.1f, xs.y * 0.1f);
    }
    __syncthreads();
    float2 acc[16];
    for (int j = 9; j >= 1; j--) {
        int q = 0;
        for (int e = t; e < 4096; e += 256, q++) {
            int r = e >> 6, c = e & 63;
            float2 a2 = make_float2(0.f, 0.f);
            for (int k = 0; k < 64; k++) cmac(a2, X[r * 64 + k], R[k * 64 + c]);
            acc[q] = a2;
        }
        __syncthreads();
        float inv = 1.f / (float)j;
        q = 0;
        for (int e = t; e < 4096; e += 256, q++) {
            int r = e >> 6, c = e & 63;
            R[e] = make_float2(((r == c) ? 1.f : 0.f) + acc[q].x * inv, acc[q].y * inv);
        }
        __syncthreads();
    }
    for (int sq = 0; sq < s; sq++) {
        int q = 0;
        for (int e = t; e < 4096; e += 256, q++) {
            int r = e >> 6, c = e & 63;
            float2 a2 = make_float2(0.f, 0.f);
            for (int k = 0; k < 64; k++) cmac(a2, R[r * 64 + k], R[k * 64 + c]);
            acc[q] = a2;
        }
        __syncthreads();
        q = 0;
        for (int e = t; e < 4096; e += 256, q++) R[e] = acc[q];
        __syncthreads();
    }
    for (int e = t; e < 4096; e += 256) {
        int r = e >> 6, c = e & 63;
        float ang = php * (float)(r & 7) + pre_i * (float)(c >> 3) + pre_j * (float)(c & 7);
        float sn, cs; __sincosf(ang, &sn, &cs);
        float2 v = cmul(make_float2(cs, sn), R[e]);
        bsm[blk * 4096 + c * 64 + r] = v;   // transposed: [k][o]
    }
}

// ---------------------------------------------------------------------------
// Main simulation kernel. 1 block (256 thr) / sample, state in swizzled LDS.
// ---------------------------------------------------------------------------

// Two-mode gate: lane = fiber (64 fibers), wave wq owns outputs o in
// [16wq, 16wq+16). Per k: one lane-parallel LDS read + 16 cmacs with
// wave-uniform (scalar-loaded) G. Barrier between read and write phases
// (fibers are shared across waves).
template<int M1, int M2>
__device__ __attribute__((noinline)) void bs_gate(
    float2* S, const float2* __restrict__ Gt, int lane, int wq) {
    constexpr int st1 = 512 >> (3 * M1);
    constexpr int st2 = 512 >> (3 * M2);
    constexpr int freeA = (M1 != 0 && M2 != 0) ? 0 : ((M1 != 1 && M2 != 1) ? 1 : 2);
    constexpr int freeB = (M1 != 3 && M2 != 3) ? 3 : ((M1 != 2 && M2 != 2) ? 2 : 1);
    constexpr int sa = 512 >> (3 * freeA);
    constexpr int sb = 512 >> (3 * freeB);
    int fbase = (lane >> 3) * sa + (lane & 7) * sb;
    int pb = pidx(fbase);
    float2 acc[16];
    #pragma unroll
    for (int j = 0; j < 16; j++) acc[j] = make_float2(0.f, 0.f);
    const float2* __restrict__ g0 = Gt + wq * 16;
    #pragma unroll 1
    for (int ka = 0; ka < 8; ka++) {
        int eA = ka * st1;
        int vA = pb ^ (eA ^ swz(eA));
        const float2* __restrict__ gka = g0 + ka * 512;
        #pragma unroll
        for (int kb = 0; kb < 8; kb++) {
            int eB = kb * st2;                       // compile-time
            float2 sv = S[vA ^ (eB ^ swz(eB))];
            const float2* __restrict__ gk = gka + kb * 64;
            #pragma unroll
            for (int j = 0; j < 16; j++) cmac(acc[j], gk[j], sv);
        }
    }
    __syncthreads();
    {
        int eoW = (wq * 2) * st1;
        int pwW = eoW ^ swz(eoW);
        #pragma unroll
        for (int j = 0; j < 16; j++) {
            int eoJ = (j >> 3) * st1 + (j & 7) * st2; // compile-time
            S[pb ^ pwW ^ (eoJ ^ swz(eoJ))] = acc[j];
        }
    }
    __syncthreads();
}

// Single-mode 8x8 gate; thread owns 2 private fibers -> no mid-barrier.
// Ut stored transposed [k*8+i].
template<int MODE>
__device__ __attribute__((noinline)) void one_gate(
    float2* S, const float2* __restrict__ Ut, int t) {
    constexpr int st = 512 >> (3 * MODE);
    constexpr int F0 = (MODE == 0) ? 64 : 512;
    constexpr int F1 = (MODE <= 1) ? 8 : 64;
    constexpr int F2 = (MODE == 3) ? 8 : 1;
    int f0 = t, f1 = t + 256;
    int fb0 = ((f0 >> 6) & 7) * F0 + ((f0 >> 3) & 7) * F1 + (f0 & 7) * F2;
    int fb1 = ((f1 >> 6) & 7) * F0 + ((f1 >> 3) & 7) * F1 + (f1 & 7) * F2;
    int pb0 = pidx(fb0), pb1 = pidx(fb1);
    float2 a0[8], a1[8];
    #pragma unroll
    for (int i = 0; i < 8; i++) { a0[i] = make_float2(0.f, 0.f); a1[i] = make_float2(0.f, 0.f); }
    #pragma unroll
    for (int k = 0; k < 8; k++) {
        int eK = k * st;
        int pk = eK ^ swz(eK);                       // compile-time
        float2 s0 = S[pb0 ^ pk];
        float2 s1 = S[pb1 ^ pk];
        const float2* __restrict__ gk = Ut + k * 8;
        #pragma unroll
        for (int i = 0; i < 8; i++) { cmac(a0[i], gk[i], s0); cmac(a1[i], gk[i], s1); }
    }
    #pragma unroll
    for (int i = 0; i < 8; i++) {
        int eI = i * st;
        int pi = eI ^ swz(eI);
        S[pb0 ^ pi] = a0[i];
        S[pb1 ^ pi] = a1[i];
    }
    __syncthreads();
}

__global__ __launch_bounds__(256, 4) void sim_kernel(
    const float* __restrict__ coh, const float2* __restrict__ sqm,
    const float2* __restrict__ dpm, const float2* __restrict__ bsm,
    float* __restrict__ out) {
    __shared__ float2 S[AMPS];
    __shared__ float ch[32];
    __shared__ float red[16];
    int b = blockIdx.x;
    int t = threadIdx.x;
    int lane = t & 63;
    int wq = __builtin_amdgcn_readfirstlane(t >> 6);

    if (t < 32) ch[t] = coh[b * 32 + t];
    __syncthreads();
    for (int e = t; e < AMPS; e += 256) {
        float v = ch[e >> 9] * ch[8 + ((e >> 6) & 7)] * ch[16 + ((e >> 3) & 7)] * ch[24 + (e & 7)];
        S[pidx(e)] = make_float2(v, 0.f);
    }
    __syncthreads();

    #pragma unroll 1
    for (int l = 0; l < NL; l++) {
        const float2* g1 = bsm + (size_t)(l * 12) * 4096;
        bs_gate<0, 1>(S, g1 + 0 * 4096, lane, wq);
        bs_gate<0, 2>(S, g1 + 1 * 4096, lane, wq);
        bs_gate<0, 3>(S, g1 + 2 * 4096, lane, wq);
        bs_gate<1, 2>(S, g1 + 3 * 4096, lane, wq);
        bs_gate<1, 3>(S, g1 + 4 * 4096, lane, wq);
        bs_gate<2, 3>(S, g1 + 5 * 4096, lane, wq);
        const float2* sq = sqm + (size_t)(l * 4) * 64;
        one_gate<0>(S, sq + 0 * 64, t);
        one_gate<1>(S, sq + 1 * 64, t);
        one_gate<2>(S, sq + 2 * 64, t);
        one_gate<3>(S, sq + 3 * 64, t);
        const float2* g2 = bsm + (size_t)(l * 12 + 6) * 4096;
        bs_gate<0, 1>(S, g2 + 0 * 4096, lane, wq);
        bs_gate<0, 2>(S, g2 + 1 * 4096, lane, wq);
        bs_gate<0, 3>(S, g2 + 2 * 4096, lane, wq);
        bs_gate<1, 2>(S, g2 + 3 * 4096, lane, wq);
        bs_gate<1, 3>(S, g2 + 4 * 4096, lane, wq);
        bs_gate<2, 3>(S, g2 + 5 * 4096, lane, wq);
        const float2* dp = dpm + (size_t)(l * 4) * 64;
        one_gate<0>(S, dp + 0 * 64, t);
        one_gate<1>(S, dp + 1 * 64, t);
        one_gate<2>(S, dp + 2 * 64, t);
        one_gate<3>(S, dp + 3 * 64, t);
    }

    // <n_w> per mode; iterate physical slots, recover logical index (involution).
    float ev0 = 0.f, ev1 = 0.f, ev2 = 0.f, ev3 = 0.f;
    for (int q = t; q < AMPS; q += 256) {
        float2 s = S[q];
        int e = pidx(q);
        float pr = s.x * s.x + s.y * s.y;
        ev0 += pr * (float)(e >> 9);
        ev1 += pr * (float)((e >> 6) & 7);
        ev2 += pr * (float)((e >> 3) & 7);
        ev3 += pr * (float)(e & 7);
    }
    #pragma unroll
    for (int off = 32; off > 0; off >>= 1) {
        ev0 += __shfl_down(ev0, off);
        ev1 += __shfl_down(ev1, off);
        ev2 += __shfl_down(ev2, off);
        ev3 += __shfl_down(ev3, off);
    }
    __syncthreads();
    if (lane == 0) {
        red[wq * 4 + 0] = ev0;
        red[wq * 4 + 1] = ev1;
        red[wq * 4 + 2] = ev2;
        red[wq * 4 + 3] = ev3;
    }
    __syncthreads();
    if (t < 4) out[b * 4 + t] = red[t] + red[4 + t] + red[8 + t] + red[12 + t];
}

extern "C" void kernel_launch(void* const* d_in, const int* in_sizes, int n_in,
                              void* d_out, int out_size, void* d_ws, size_t ws_size,
                              hipStream_t stream) {
    const float* x    = (const float*)d_in[0];
    const float* th1  = (const float*)d_in[1];
    const float* ph1  = (const float*)d_in[2];
    const float* th2  = (const float*)d_in[3];
    const float* ph2  = (const float*)d_in[4];
    const float* dpr  = (const float*)d_in[5];
    const float* dpph = (const float*)d_in[6];
    const float* sqr  = (const float*)d_in[7];
    const float* sqph = (const float*)d_in[8];
    const float* kerr = (const float*)d_in[9];
    float* out = (float*)d_out;

    int Bn = in_sizes[0] / NM;

    char* ws = (char*)d_ws;
    float*  coh = (float*)ws;                          // Bn*32 floats
    size_t coh_bytes = (size_t)Bn * 32 * sizeof(float);
    float2* sqm = (float2*)(ws + coh_bytes);           // 16*64 float2
    float2* dpm = (float2*)(ws + coh_bytes + 16 * 64 * sizeof(float2));
    float2* bsm = (float2*)(ws + coh_bytes + 32 * 64 * sizeof(float2)); // 48*4096 float2

    int total = Bn * NM;
    coh_kernel<<<(total + 255) / 256, 256, 0, stream>>>(x, coh, total);
    expm8_kernel<<<32, 64, 0, stream>>>(sqr, sqph, dpr, dpph, kerr, sqm, dpm);
    expm64_kernel<<<48, 256, 0, stream>>>(th1, ph1, th2, ph2, bsm);
    sim_kernel<<<Bn, 256, 0, stream>>>(coh, sqm, dpm, bsm, out);
}

// Round 3
// 3218.636 us; speedup vs baseline: 4.8054x; 3.8490x over previous
//
#include <hip/hip_runtime.h>

// CV quantum neural network simulator, D=8 cutoff, M=4 modes, L=4 layers.
// R3: photon-number-sparse BS application (344/4096 nonzeros, exact), fully
// unrolled per-wave templates; new F2-linear LDS swizzle (conflict-free for
// every access pattern); compact G layout (4KB/gate).

#define NM 4
#define NL 4
#define AMPS 4096

__device__ __forceinline__ void cmac(float2& acc, float2 a, float2 b) {
    acc.x = fmaf(a.x, b.x, acc.x);
    acc.x = fmaf(-a.y, b.y, acc.x);
    acc.y = fmaf(a.x, b.y, acc.y);
    acc.y = fmaf(a.y, b.x, acc.y);
}
__device__ __forceinline__ float2 cmul(float2 a, float2 b) {
    return make_float2(a.x * b.x - a.y * b.y, a.x * b.y + a.y * b.x);
}

// F2-linear physical-slot map. Digits d0=e[2:0], d1=e[5:3], d2=e[8:6],
// d3=e[11:9]. low3(phys) = d0 ^ rot1(d1) ^ rot2(d2) ^ d3; bit3 = e3^e6^e9.
// Verified bijective on every 16-lane quarter-wave subspace used below.
__device__ __forceinline__ int physw(int e) {
    int l0 = ((e >> 0) ^ (e >> 5) ^ (e >> 7) ^ (e >> 9)) & 1;
    int l1 = ((e >> 1) ^ (e >> 3) ^ (e >> 8) ^ (e >> 10)) & 1;
    int l2 = ((e >> 2) ^ (e >> 4) ^ (e >> 6) ^ (e >> 11)) & 1;
    int l3 = ((e >> 3) ^ (e >> 6) ^ (e >> 9)) & 1;
    return (e & ~15) | l0 | (l1 << 1) | (l2 << 2) | (l3 << 3);
}

// ---------------------------------------------------------------------------
// Kernel 1: coherent vectors = first column of expm(x*(AD - A)).
// ---------------------------------------------------------------------------
__global__ void coh_kernel(const float* __restrict__ x, float* __restrict__ coh, int total) {
    int t = blockIdx.x * blockDim.x + threadIdx.x;
    if (t >= total) return;
    float alpha = x[t];
    const float sq1 = 1.0f, sq2 = 1.41421356f, sq3 = 1.73205081f, sq4 = 2.0f,
                sq5 = 2.23606798f, sq6 = 2.44948975f, sq7 = 2.64575131f;
    float v0 = 1.f, v1 = 0.f, v2 = 0.f, v3 = 0.f, v4 = 0.f, v5 = 0.f, v6 = 0.f, v7 = 0.f;
    const int NS = 32;
    float h = alpha / (float)NS;
    for (int s = 0; s < NS; s++) {
        float w0 = v0, w1 = v1, w2 = v2, w3 = v3, w4 = v4, w5 = v5, w6 = v6, w7 = v7;
        float t0 = v0, t1 = v1, t2 = v2, t3 = v3, t4 = v4, t5 = v5, t6 = v6, t7 = v7;
        #pragma unroll
        for (int j = 1; j <= 8; j++) {
            float c = h / (float)j;
            float n0 = c * (          - sq1 * t1);
            float n1 = c * (sq1 * t0 - sq2 * t2);
            float n2 = c * (sq2 * t1 - sq3 * t3);
            float n3 = c * (sq3 * t2 - sq4 * t4);
            float n4 = c * (sq4 * t3 - sq5 * t5);
            float n5 = c * (sq5 * t4 - sq6 * t6);
            float n6 = c * (sq6 * t5 - sq7 * t7);
            float n7 = c * (sq7 * t6            );
            t0 = n0; t1 = n1; t2 = n2; t3 = n3; t4 = n4; t5 = n5; t6 = n6; t7 = n7;
            w0 += t0; w1 += t1; w2 += t2; w3 += t3; w4 += t4; w5 += t5; w6 += t6; w7 += t7;
        }
        v0 = w0; v1 = w1; v2 = w2; v3 = w3; v4 = w4; v5 = w5; v6 = w6; v7 = w7;
    }
    float* dst = coh + t * 8;
    dst[0] = v0; dst[1] = v1; dst[2] = v2; dst[3] = v3;
    dst[4] = v4; dst[5] = v5; dst[6] = v6; dst[7] = v7;
}

// ---------------------------------------------------------------------------
// Kernel 2: 8x8 complex expm. Blocks 0..15: squeeze. Blocks 16..31:
// displacement with Kerr folded (row scale). Stored transposed [k*8+i].
// ---------------------------------------------------------------------------
__global__ __launch_bounds__(64) void expm8_kernel(
    const float* __restrict__ sqr, const float* __restrict__ sqph,
    const float* __restrict__ dpr, const float* __restrict__ dpph,
    const float* __restrict__ kerr,
    float2* __restrict__ sqm, float2* __restrict__ dpm) {
    __shared__ float2 X[64], R[64];
    int t = threadIdx.x;
    int r = t >> 3, c = t & 7;
    int bid = blockIdx.x;
    float2 h = make_float2(0.f, 0.f);
    float normb;
    if (bid < 16) {
        float rr = sqr[bid], ph = sqph[bid];
        float zr = rr * cosf(ph), zi = rr * sinf(ph);
        if (c == r + 2) { float f = 0.5f * sqrtf((float)((r + 1) * (r + 2))); h.x =  f * zr; h.y = -f * zi; }
        if (r == c + 2) { float f = 0.5f * sqrtf((float)((c + 1) * (c + 2))); h.x = -f * zr; h.y = -f * zi; }
        normb = fabsf(rr) * 5.5f;
    } else {
        int g = bid - 16;
        float rr = dpr[g], ph = dpph[g];
        float am = rr * cosf(ph);
        float aph = rr * sinf(ph);
        float ar = am * cosf(aph), ai = am * sinf(aph);
        if (r == c + 1) { float f = sqrtf((float)r); h.x += ar * f; h.y += ai * f; }
        if (c == r + 1) { float f = sqrtf((float)c); h.x -= ar * f; h.y += ai * f; }
        normb = fabsf(am) * 5.5f;
    }
    int s = 0;
    while (normb > 0.2f && s < 20) { normb *= 0.5f; s++; }
    float fs = 1.f;
    for (int q = 0; q < s; q++) fs *= 0.5f;
    float2 xs = make_float2(h.x * fs, h.y * fs);
    X[t] = xs;
    float idel = (r == c) ? 1.f : 0.f;
    R[t] = make_float2(idel + xs.x / 9.f, xs.y / 9.f);
    __syncthreads();
    for (int j = 8; j >= 1; j--) {
        float2 acc = make_float2(0.f, 0.f);
        #pragma unroll
        for (int k = 0; k < 8; k++) cmac(acc, X[r * 8 + k], R[k * 8 + c]);
        __syncthreads();
        float inv = 1.f / (float)j;
        R[t] = make_float2(idel + acc.x * inv, acc.y * inv);
        __syncthreads();
    }
    for (int q = 0; q < s; q++) {
        float2 acc = make_float2(0.f, 0.f);
        #pragma unroll
        for (int k = 0; k < 8; k++) cmac(acc, R[r * 8 + k], R[k * 8 + c]);
        __syncthreads();
        R[t] = acc;
        __syncthreads();
    }
    float2 v = R[t];
    if (bid >= 16) {
        float kp = kerr[bid - 16];
        float ang = kp * (float)(r * r);
        float sn, cs; __sincosf(ang, &sn, &cs);
        v = cmul(make_float2(cs, sn), v);
        dpm[(bid - 16) * 64 + c * 8 + r] = v;
    } else {
        sqm[bid * 64 + c * 8 + r] = v;
    }
}

// ---------------------------------------------------------------------------
// Kernel 3: 64x64 complex expm for 48 beamsplitters, diag rotations folded.
// Output: COMPACT photon-number-sparse layout, fixed stride 8:
//   bsG[blk*512 + o*8 + j] = U'[o][k], k=(amin+j)*8 + (n-amin-j), j<c(n(o)).
// ---------------------------------------------------------------------------
__global__ __launch_bounds__(256) void expm64_kernel(
    const float* __restrict__ th1, const float* __restrict__ ph1,
    const float* __restrict__ th2, const float* __restrict__ ph2,
    float2* __restrict__ bsG) {
    __shared__ float2 X[4096], R[4096];
    int blk = blockIdx.x;
    int l = blk / 12, idx = blk % 12;
    int p = (idx < 6) ? idx : idx - 6;
    int mi = (p < 3) ? 0 : ((p < 5) ? 1 : 2);
    int mj = (p == 0) ? 1 : ((p == 1 || p == 3) ? 2 : 3);
    const float* th = (idx < 6) ? th1 : th2;
    const float* ph = (idx < 6) ? ph1 : ph2;
    float tt = th[l * 16 + mi * 4 + mj];
    float pp = ph[l * 16 + mi * 4 + mj];
    float cp = cosf(pp), sp = sinf(pp);
    float php = ph[l * 16 + mj * 4 + mi];
    float pre_i = 0.f, pre_j = 0.f;
    if (p == 0) { pre_i = ph[l * 16 + 0]; pre_j = ph[l * 16 + 5]; }
    else if (p == 1) { pre_j = ph[l * 16 + 10]; }
    else if (p == 2) { pre_j = ph[l * 16 + 15]; }
    int t = threadIdx.x;
    float normb = fabsf(tt) * 13.94f;
    int s = 0;
    while (normb > 0.2f && s < 20) { normb *= 0.5f; s++; }
    float fs = 1.f;
    for (int q = 0; q < s; q++) fs *= 0.5f;
    for (int e = t; e < 4096; e += 256) {
        int r = e >> 6, c = e & 63;
        int a = r >> 3, b = r & 7, ca = c >> 3, cb = c & 7;
        float2 h = make_float2(0.f, 0.f);
        if (ca == a + 1 && cb == b - 1) {
            float g = tt * sqrtf((float)((a + 1) * b));
            h.x = g * cp; h.y = g * sp;
        } else if (ca == a - 1 && cb == b + 1) {
            float g = tt * sqrtf((float)(a * (b + 1)));
            h.x = -g * cp; h.y = g * sp;
        }
        float2 xs = make_float2(h.x * fs, h.y * fs);
        X[e] = xs;
        R[e] = make_float2(((r == c) ? 1.f : 0.f) + xs.x * 0.1f, xs.y * 0.1f);
    }
    __syncthreads();
    float2 acc[16];
    for (int j = 9; j >= 1; j--) {
        int q = 0;
        for (int e = t; e < 4096; e += 256, q++) {
            int r = e >> 6, c = e & 63;
            float2 a2 = make_float2(0.f, 0.f);
            for (int k = 0; k < 64; k++) cmac(a2, X[r * 64 + k], R[k * 64 + c]);
            acc[q] = a2;
        }
        __syncthreads();
        float inv = 1.f / (float)j;
        q = 0;
        for (int e = t; e < 4096; e += 256, q++) {
            int r = e >> 6, c = e & 63;
            R[e] = make_float2(((r == c) ? 1.f : 0.f) + acc[q].x * inv, acc[q].y * inv);
        }
        __syncthreads();
    }
    for (int sq = 0; sq < s; sq++) {
        int q = 0;
        for (int e = t; e < 4096; e += 256, q++) {
            int r = e >> 6, c = e & 63;
            float2 a2 = make_float2(0.f, 0.f);
            for (int k = 0; k < 64; k++) cmac(a2, R[r * 64 + k], R[k * 64 + c]);
            acc[q] = a2;
        }
        __syncthreads();
        q = 0;
        for (int e = t; e < 4096; e += 256, q++) R[e] = acc[q];
        __syncthreads();
    }
    // Compact sparse write, phases folded: row phase on o, col phase on k.
    for (int e = t; e < 512; e += 256) {
        int o = e >> 3, j = e & 7;
        int n = (o >> 3) + (o & 7);
        int amin = max(0, n - 7);
        int cnt = min(n + 1, 15 - n);
        if (j < cnt) {
            int ka = amin + j, kb = n - ka;
            int k = ka * 8 + kb;
            float ang = php * (float)(o & 7) + pre_i * (float)ka + pre_j * (float)kb;
            float sn, cs; __sincosf(ang, &sn, &cs);
            bsG[blk * 512 + o * 8 + j] = cmul(make_float2(cs, sn), R[o * 64 + k]);
        }
    }
}

// ---------------------------------------------------------------------------
// Main simulation kernel. 1 block (256 thr)/sample, state in swizzled LDS.
// ---------------------------------------------------------------------------

// Sparse two-mode gate. lane = fiber; wave WQ owns output rows a'=2WQ,2WQ+1.
// Fully unrolled: all S offsets / G offsets compile-time. Reads shared
// between the <=2 outputs of equal photon number n.
template<int M1, int M2, int WQ>
__device__ __attribute__((noinline)) void bs_gate(
    float2* S, const float2* __restrict__ Gt, int lane) {
    constexpr int st1 = 512 >> (3 * M1);
    constexpr int st2 = 512 >> (3 * M2);
    constexpr int freeA = (M1 != 0 && M2 != 0) ? 0 : ((M1 != 1 && M2 != 1) ? 1 : 2);
    constexpr int freeB = (M1 != 3 && M2 != 3) ? 3 : ((M1 != 2 && M2 != 2) ? 2 : 1);
    constexpr int sa = 512 >> (3 * freeA);
    constexpr int sb = 512 >> (3 * freeB);
    int fbase = (lane >> 3) * sa + (lane & 7) * sb;
    int pb = physw(fbase);
    float2 acc[16];
    #pragma unroll
    for (int j = 0; j < 16; j++) acc[j] = make_float2(0.f, 0.f);
    #pragma unroll
    for (int n = 2 * WQ; n <= 2 * WQ + 8; n++) {
        const int amin = (n > 7) ? (n - 7) : 0;
        const int b1 = n - 2 * WQ;          // output (2WQ,   b1) -> acc[b1]
        const int b2 = n - 2 * WQ - 1;      // output (2WQ+1, b2) -> acc[8+b2]
        #pragma unroll
        for (int ka = 0; ka < 8; ka++) {
            if (ka >= amin && ka <= ((n < 7) ? n : 7)) {
                const int kb = n - ka;
                const int pk = physw(ka * st1 + kb * st2);   // folds to const
                float2 sv = S[pb ^ pk];
                if (b1 >= 0 && b1 <= 7) {
                    float2 g = Gt[(16 * WQ + b1) * 8 + (ka - amin)];
                    cmac(acc[b1], g, sv);
                }
                if (b2 >= 0 && b2 <= 7) {
                    float2 g = Gt[(16 * WQ + 8 + b2) * 8 + (ka - amin)];
                    cmac(acc[8 + b2], g, sv);
                }
            }
        }
    }
    __syncthreads();
    #pragma unroll
    for (int j = 0; j < 16; j++) {
        const int a = 2 * WQ + (j >> 3), b = j & 7;
        const int po = physw(a * st1 + b * st2);             // folds to const
        S[pb ^ po] = acc[j];
    }
    __syncthreads();
}

template<int M1, int M2>
__device__ __forceinline__ void do_bs(float2* S, const float2* __restrict__ Gt,
                                      int lane, int wq) {
    switch (wq) {
        case 0: bs_gate<M1, M2, 0>(S, Gt, lane); break;
        case 1: bs_gate<M1, M2, 1>(S, Gt, lane); break;
        case 2: bs_gate<M1, M2, 2>(S, Gt, lane); break;
        default: bs_gate<M1, M2, 3>(S, Gt, lane); break;
    }
}

// Single-mode 8x8 dense gate; thread owns 2 private fibers. Ut transposed [k*8+i].
template<int MODE>
__device__ __attribute__((noinline)) void one_gate(
    float2* S, const float2* __restrict__ Ut, int t) {
    constexpr int st = 512 >> (3 * MODE);
    constexpr int F0 = (MODE == 0) ? 64 : 512;
    constexpr int F1 = (MODE <= 1) ? 8 : 64;
    constexpr int F2 = (MODE == 3) ? 8 : 1;
    int f0 = t, f1 = t + 256;
    int fb0 = ((f0 >> 6) & 7) * F0 + ((f0 >> 3) & 7) * F1 + (f0 & 7) * F2;
    int fb1 = ((f1 >> 6) & 7) * F0 + ((f1 >> 3) & 7) * F1 + (f1 & 7) * F2;
    int pb0 = physw(fb0), pb1 = physw(fb1);
    float2 a0[8], a1[8];
    #pragma unroll
    for (int i = 0; i < 8; i++) { a0[i] = make_float2(0.f, 0.f); a1[i] = make_float2(0.f, 0.f); }
    #pragma unroll
    for (int k = 0; k < 8; k++) {
        const int pk = physw(k * st);
        float2 s0 = S[pb0 ^ pk];
        float2 s1 = S[pb1 ^ pk];
        const float2* __restrict__ gk = Ut + k * 8;
        #pragma unroll
        for (int i = 0; i < 8; i++) { cmac(a0[i], gk[i], s0); cmac(a1[i], gk[i], s1); }
    }
    #pragma unroll
    for (int i = 0; i < 8; i++) {
        const int pi = physw(i * st);
        S[pb0 ^ pi] = a0[i];
        S[pb1 ^ pi] = a1[i];
    }
    __syncthreads();
}

__global__ __launch_bounds__(256, 4) void sim_kernel(
    const float* __restrict__ coh, const float2* __restrict__ sqm,
    const float2* __restrict__ dpm, const float2* __restrict__ bsG,
    float* __restrict__ out) {
    __shared__ float2 S[AMPS];
    __shared__ float ch[32];
    __shared__ float red[16];
    int b = blockIdx.x;
    int t = threadIdx.x;
    int lane = t & 63;
    int wq = __builtin_amdgcn_readfirstlane(t >> 6);

    if (t < 32) ch[t] = coh[b * 32 + t];
    __syncthreads();
    for (int e = t; e < AMPS; e += 256) {
        float v = ch[e >> 9] * ch[8 + ((e >> 6) & 7)] * ch[16 + ((e >> 3) & 7)] * ch[24 + (e & 7)];
        S[physw(e)] = make_float2(v, 0.f);
    }
    __syncthreads();

    #pragma unroll 1
    for (int l = 0; l < NL; l++) {
        const float2* g1 = bsG + (size_t)(l * 12) * 512;
        do_bs<0, 1>(S, g1 + 0 * 512, lane, wq);
        do_bs<0, 2>(S, g1 + 1 * 512, lane, wq);
        do_bs<0, 3>(S, g1 + 2 * 512, lane, wq);
        do_bs<1, 2>(S, g1 + 3 * 512, lane, wq);
        do_bs<1, 3>(S, g1 + 4 * 512, lane, wq);
        do_bs<2, 3>(S, g1 + 5 * 512, lane, wq);
        const float2* sq = sqm + (size_t)(l * 4) * 64;
        one_gate<0>(S, sq + 0 * 64, t);
        one_gate<1>(S, sq + 1 * 64, t);
        one_gate<2>(S, sq + 2 * 64, t);
        one_gate<3>(S, sq + 3 * 64, t);
        const float2* g2 = bsG + (size_t)(l * 12 + 6) * 512;
        do_bs<0, 1>(S, g2 + 0 * 512, lane, wq);
        do_bs<0, 2>(S, g2 + 1 * 512, lane, wq);
        do_bs<0, 3>(S, g2 + 2 * 512, lane, wq);
        do_bs<1, 2>(S, g2 + 3 * 512, lane, wq);
        do_bs<1, 3>(S, g2 + 4 * 512, lane, wq);
        do_bs<2, 3>(S, g2 + 5 * 512, lane, wq);
        const float2* dp = dpm + (size_t)(l * 4) * 64;
        one_gate<0>(S, dp + 0 * 64, t);
        one_gate<1>(S, dp + 1 * 64, t);
        one_gate<2>(S, dp + 2 * 64, t);
        one_gate<3>(S, dp + 3 * 64, t);
    }

    // <n_w> per mode: iterate logical index, read physical slot.
    float ev0 = 0.f, ev1 = 0.f, ev2 = 0.f, ev3 = 0.f;
    for (int e = t; e < AMPS; e += 256) {
        float2 s = S[physw(e)];
        float pr = s.x * s.x + s.y * s.y;
        ev0 += pr * (float)(e >> 9);
        ev1 += pr * (float)((e >> 6) & 7);
        ev2 += pr * (float)((e >> 3) & 7);
        ev3 += pr * (float)(e & 7);
    }
    #pragma unroll
    for (int off = 32; off > 0; off >>= 1) {
        ev0 += __shfl_down(ev0, off);
        ev1 += __shfl_down(ev1, off);
        ev2 += __shfl_down(ev2, off);
        ev3 += __shfl_down(ev3, off);
    }
    __syncthreads();
    if (lane == 0) {
        red[wq * 4 + 0] = ev0;
        red[wq * 4 + 1] = ev1;
        red[wq * 4 + 2] = ev2;
        red[wq * 4 + 3] = ev3;
    }
    __syncthreads();
    if (t < 4) out[b * 4 + t] = red[t] + red[4 + t] + red[8 + t] + red[12 + t];
}

extern "C" void kernel_launch(void* const* d_in, const int* in_sizes, int n_in,
                              void* d_out, int out_size, void* d_ws, size_t ws_size,
                              hipStream_t stream) {
    const float* x    = (const float*)d_in[0];
    const float* th1  = (const float*)d_in[1];
    const float* ph1  = (const float*)d_in[2];
    const float* th2  = (const float*)d_in[3];
    const float* ph2  = (const float*)d_in[4];
    const float* dpr  = (const float*)d_in[5];
    const float* dpph = (const float*)d_in[6];
    const float* sqr  = (const float*)d_in[7];
    const float* sqph = (const float*)d_in[8];
    const float* kerr = (const float*)d_in[9];
    float* out = (float*)d_out;

    int Bn = in_sizes[0] / NM;

    char* ws = (char*)d_ws;
    float*  coh = (float*)ws;                          // Bn*32 floats
    size_t coh_bytes = (size_t)Bn * 32 * sizeof(float);
    float2* sqm = (float2*)(ws + coh_bytes);           // 16*64 float2
    float2* dpm = (float2*)(ws + coh_bytes + 16 * 64 * sizeof(float2));
    float2* bsG = (float2*)(ws + coh_bytes + 32 * 64 * sizeof(float2)); // 48*512 float2

    int total = Bn * NM;
    coh_kernel<<<(total + 255) / 256, 256, 0, stream>>>(x, coh, total);
    expm8_kernel<<<32, 64, 0, stream>>>(sqr, sqph, dpr, dpph, kerr, sqm, dpm);
    expm64_kernel<<<48, 256, 0, stream>>>(th1, ph1, th2, ph2, bsG);
    sim_kernel<<<Bn, 256, 0, stream>>>(coh, sqm, dpm, bsG, out);
}

// Round 4
// 1553.072 us; speedup vs baseline: 9.9589x; 2.0724x over previous
//
#include <hip/hip_runtime.h>

// CV quantum neural network simulator, D=8 cutoff, M=4 modes, L=4 layers.
// R4: same sparse algorithm as R3, but gate helpers are __forceinline__
// (R3's noinline callees spilled acc[16] to scratch -> 8 GB HBM traffic).
// Interferometer halves looped (not unrolled) to bound code size.

#define NM 4
#define NL 4
#define AMPS 4096

__device__ __forceinline__ void cmac(float2& acc, float2 a, float2 b) {
    acc.x = fmaf(a.x, b.x, acc.x);
    acc.x = fmaf(-a.y, b.y, acc.x);
    acc.y = fmaf(a.x, b.y, acc.y);
    acc.y = fmaf(a.y, b.x, acc.y);
}
__device__ __forceinline__ float2 cmul(float2 a, float2 b) {
    return make_float2(a.x * b.x - a.y * b.y, a.x * b.y + a.y * b.x);
}

// F2-linear physical-slot map (bank-conflict-free for all access patterns).
__device__ __forceinline__ int physw(int e) {
    int l0 = ((e >> 0) ^ (e >> 5) ^ (e >> 7) ^ (e >> 9)) & 1;
    int l1 = ((e >> 1) ^ (e >> 3) ^ (e >> 8) ^ (e >> 10)) & 1;
    int l2 = ((e >> 2) ^ (e >> 4) ^ (e >> 6) ^ (e >> 11)) & 1;
    int l3 = ((e >> 3) ^ (e >> 6) ^ (e >> 9)) & 1;
    return (e & ~15) | l0 | (l1 << 1) | (l2 << 2) | (l3 << 3);
}

// ---------------------------------------------------------------------------
// Kernel 1: coherent vectors = first column of expm(x*(AD - A)).
// ---------------------------------------------------------------------------
__global__ void coh_kernel(const float* __restrict__ x, float* __restrict__ coh, int total) {
    int t = blockIdx.x * blockDim.x + threadIdx.x;
    if (t >= total) return;
    float alpha = x[t];
    const float sq1 = 1.0f, sq2 = 1.41421356f, sq3 = 1.73205081f, sq4 = 2.0f,
                sq5 = 2.23606798f, sq6 = 2.44948975f, sq7 = 2.64575131f;
    float v0 = 1.f, v1 = 0.f, v2 = 0.f, v3 = 0.f, v4 = 0.f, v5 = 0.f, v6 = 0.f, v7 = 0.f;
    const int NS = 32;
    float h = alpha / (float)NS;
    for (int s = 0; s < NS; s++) {
        float w0 = v0, w1 = v1, w2 = v2, w3 = v3, w4 = v4, w5 = v5, w6 = v6, w7 = v7;
        float t0 = v0, t1 = v1, t2 = v2, t3 = v3, t4 = v4, t5 = v5, t6 = v6, t7 = v7;
        #pragma unroll
        for (int j = 1; j <= 8; j++) {
            float c = h / (float)j;
            float n0 = c * (          - sq1 * t1);
            float n1 = c * (sq1 * t0 - sq2 * t2);
            float n2 = c * (sq2 * t1 - sq3 * t3);
            float n3 = c * (sq3 * t2 - sq4 * t4);
            float n4 = c * (sq4 * t3 - sq5 * t5);
            float n5 = c * (sq5 * t4 - sq6 * t6);
            float n6 = c * (sq6 * t5 - sq7 * t7);
            float n7 = c * (sq7 * t6            );
            t0 = n0; t1 = n1; t2 = n2; t3 = n3; t4 = n4; t5 = n5; t6 = n6; t7 = n7;
            w0 += t0; w1 += t1; w2 += t2; w3 += t3; w4 += t4; w5 += t5; w6 += t6; w7 += t7;
        }
        v0 = w0; v1 = w1; v2 = w2; v3 = w3; v4 = w4; v5 = w5; v6 = w6; v7 = w7;
    }
    float* dst = coh + t * 8;
    dst[0] = v0; dst[1] = v1; dst[2] = v2; dst[3] = v3;
    dst[4] = v4; dst[5] = v5; dst[6] = v6; dst[7] = v7;
}

// ---------------------------------------------------------------------------
// Kernel 2: 8x8 complex expm. Blocks 0..15: squeeze. Blocks 16..31:
// displacement with Kerr folded (row scale). Stored transposed [k*8+i].
// ---------------------------------------------------------------------------
__global__ __launch_bounds__(64) void expm8_kernel(
    const float* __restrict__ sqr, const float* __restrict__ sqph,
    const float* __restrict__ dpr, const float* __restrict__ dpph,
    const float* __restrict__ kerr,
    float2* __restrict__ sqm, float2* __restrict__ dpm) {
    __shared__ float2 X[64], R[64];
    int t = threadIdx.x;
    int r = t >> 3, c = t & 7;
    int bid = blockIdx.x;
    float2 h = make_float2(0.f, 0.f);
    float normb;
    if (bid < 16) {
        float rr = sqr[bid], ph = sqph[bid];
        float zr = rr * cosf(ph), zi = rr * sinf(ph);
        if (c == r + 2) { float f = 0.5f * sqrtf((float)((r + 1) * (r + 2))); h.x =  f * zr; h.y = -f * zi; }
        if (r == c + 2) { float f = 0.5f * sqrtf((float)((c + 1) * (c + 2))); h.x = -f * zr; h.y = -f * zi; }
        normb = fabsf(rr) * 5.5f;
    } else {
        int g = bid - 16;
        float rr = dpr[g], ph = dpph[g];
        float am = rr * cosf(ph);
        float aph = rr * sinf(ph);
        float ar = am * cosf(aph), ai = am * sinf(aph);
        if (r == c + 1) { float f = sqrtf((float)r); h.x += ar * f; h.y += ai * f; }
        if (c == r + 1) { float f = sqrtf((float)c); h.x -= ar * f; h.y += ai * f; }
        normb = fabsf(am) * 5.5f;
    }
    int s = 0;
    while (normb > 0.2f && s < 20) { normb *= 0.5f; s++; }
    float fs = 1.f;
    for (int q = 0; q < s; q++) fs *= 0.5f;
    float2 xs = make_float2(h.x * fs, h.y * fs);
    X[t] = xs;
    float idel = (r == c) ? 1.f : 0.f;
    R[t] = make_float2(idel + xs.x / 9.f, xs.y / 9.f);
    __syncthreads();
    for (int j = 8; j >= 1; j--) {
        float2 acc = make_float2(0.f, 0.f);
        #pragma unroll
        for (int k = 0; k < 8; k++) cmac(acc, X[r * 8 + k], R[k * 8 + c]);
        __syncthreads();
        float inv = 1.f / (float)j;
        R[t] = make_float2(idel + acc.x * inv, acc.y * inv);
        __syncthreads();
    }
    for (int q = 0; q < s; q++) {
        float2 acc = make_float2(0.f, 0.f);
        #pragma unroll
        for (int k = 0; k < 8; k++) cmac(acc, R[r * 8 + k], R[k * 8 + c]);
        __syncthreads();
        R[t] = acc;
        __syncthreads();
    }
    float2 v = R[t];
    if (bid >= 16) {
        float kp = kerr[bid - 16];
        float ang = kp * (float)(r * r);
        float sn, cs; __sincosf(ang, &sn, &cs);
        v = cmul(make_float2(cs, sn), v);
        dpm[(bid - 16) * 64 + c * 8 + r] = v;
    } else {
        sqm[bid * 64 + c * 8 + r] = v;
    }
}

// ---------------------------------------------------------------------------
// Kernel 3: 64x64 complex expm for 48 beamsplitters, diag rotations folded.
// Output: compact photon-number-sparse layout, fixed stride 8 (zero-padded):
//   bsG[blk*512 + o*8 + j] = U'[o][k], k=(amin+j)*8 + (n-amin-j), j<c(n(o)).
// ---------------------------------------------------------------------------
__global__ __launch_bounds__(256) void expm64_kernel(
    const float* __restrict__ th1, const float* __restrict__ ph1,
    const float* __restrict__ th2, const float* __restrict__ ph2,
    float2* __restrict__ bsG) {
    __shared__ float2 X[4096], R[4096];
    int blk = blockIdx.x;
    int l = blk / 12, idx = blk % 12;
    int p = (idx < 6) ? idx : idx - 6;
    int mi = (p < 3) ? 0 : ((p < 5) ? 1 : 2);
    int mj = (p == 0) ? 1 : ((p == 1 || p == 3) ? 2 : 3);
    const float* th = (idx < 6) ? th1 : th2;
    const float* ph = (idx < 6) ? ph1 : ph2;
    float tt = th[l * 16 + mi * 4 + mj];
    float pp = ph[l * 16 + mi * 4 + mj];
    float cp = cosf(pp), sp = sinf(pp);
    float php = ph[l * 16 + mj * 4 + mi];
    float pre_i = 0.f, pre_j = 0.f;
    if (p == 0) { pre_i = ph[l * 16 + 0]; pre_j = ph[l * 16 + 5]; }
    else if (p == 1) { pre_j = ph[l * 16 + 10]; }
    else if (p == 2) { pre_j = ph[l * 16 + 15]; }
    int t = threadIdx.x;
    float normb = fabsf(tt) * 13.94f;
    int s = 0;
    while (normb > 0.2f && s < 20) { normb *= 0.5f; s++; }
    float fs = 1.f;
    for (int q = 0; q < s; q++) fs *= 0.5f;
    for (int e = t; e < 4096; e += 256) {
        int r = e >> 6, c = e & 63;
        int a = r >> 3, b = r & 7, ca = c >> 3, cb = c & 7;
        float2 h = make_float2(0.f, 0.f);
        if (ca == a + 1 && cb == b - 1) {
            float g = tt * sqrtf((float)((a + 1) * b));
            h.x = g * cp; h.y = g * sp;
        } else if (ca == a - 1 && cb == b + 1) {
            float g = tt * sqrtf((float)(a * (b + 1)));
            h.x = -g * cp; h.y = g * sp;
        }
        float2 xs = make_float2(h.x * fs, h.y * fs);
        X[e] = xs;
        R[e] = make_float2(((r == c) ? 1.f : 0.f) + xs.x * 0.1f, xs.y * 0.1f);
    }
    __syncthreads();
    float2 acc[16];
    for (int j = 9; j >= 1; j--) {
        int q = 0;
        for (int e = t; e < 4096; e += 256, q++) {
            int r = e >> 6, c = e & 63;
            float2 a2 = make_float2(0.f, 0.f);
            for (int k = 0; k < 64; k++) cmac(a2, X[r * 64 + k], R[k * 64 + c]);
            acc[q] = a2;
        }
        __syncthreads();
        float inv = 1.f / (float)j;
        q = 0;
        for (int e = t; e < 4096; e += 256, q++) {
            int r = e >> 6, c = e & 63;
            R[e] = make_float2(((r == c) ? 1.f : 0.f) + acc[q].x * inv, acc[q].y * inv);
        }
        __syncthreads();
    }
    for (int sq = 0; sq < s; sq++) {
        int q = 0;
        for (int e = t; e < 4096; e += 256, q++) {
            int r = e >> 6, c = e & 63;
            float2 a2 = make_float2(0.f, 0.f);
            for (int k = 0; k < 64; k++) cmac(a2, R[r * 64 + k], R[k * 64 + c]);
            acc[q] = a2;
        }
        __syncthreads();
        q = 0;
        for (int e = t; e < 4096; e += 256, q++) R[e] = acc[q];
        __syncthreads();
    }
    for (int e = t; e < 512; e += 256) {
        int o = e >> 3, j = e & 7;
        int n = (o >> 3) + (o & 7);
        int amin = max(0, n - 7);
        int cnt = min(n + 1, 15 - n);
        float2 v = make_float2(0.f, 0.f);
        if (j < cnt) {
            int ka = amin + j, kb = n - ka;
            int k = ka * 8 + kb;
            float ang = php * (float)(o & 7) + pre_i * (float)ka + pre_j * (float)kb;
            float sn, cs; __sincosf(ang, &sn, &cs);
            v = cmul(make_float2(cs, sn), R[o * 64 + k]);
        }
        bsG[blk * 512 + o * 8 + j] = v;
    }
}

// ---------------------------------------------------------------------------
// Main simulation kernel. 1 block (256 thr)/sample, state in swizzled LDS.
// ---------------------------------------------------------------------------

// Sparse two-mode gate. lane = fiber; wave WQ owns output rows a'=2WQ,2WQ+1.
// Fully inlined and unrolled: all S/G offsets compile-time.
template<int M1, int M2, int WQ>
__device__ __forceinline__ void bs_gate(
    float2* S, const float2* __restrict__ Gt, int lane) {
    constexpr int st1 = 512 >> (3 * M1);
    constexpr int st2 = 512 >> (3 * M2);
    constexpr int freeA = (M1 != 0 && M2 != 0) ? 0 : ((M1 != 1 && M2 != 1) ? 1 : 2);
    constexpr int freeB = (M1 != 3 && M2 != 3) ? 3 : ((M1 != 2 && M2 != 2) ? 2 : 1);
    constexpr int sa = 512 >> (3 * freeA);
    constexpr int sb = 512 >> (3 * freeB);
    int fbase = (lane >> 3) * sa + (lane & 7) * sb;
    int pb = physw(fbase);
    float2 acc[16];
    #pragma unroll
    for (int j = 0; j < 16; j++) acc[j] = make_float2(0.f, 0.f);
    #pragma unroll
    for (int n = 2 * WQ; n <= 2 * WQ + 8; n++) {
        const int amin = (n > 7) ? (n - 7) : 0;
        const int b1 = n - 2 * WQ;          // output (2WQ,   b1) -> acc[b1]
        const int b2 = n - 2 * WQ - 1;      // output (2WQ+1, b2) -> acc[8+b2]
        #pragma unroll
        for (int ka = 0; ka < 8; ka++) {
            if (ka >= amin && ka <= ((n < 7) ? n : 7)) {
                const int kb = n - ka;
                const int pk = physw(ka * st1 + kb * st2);   // compile-time
                float2 sv = S[pb ^ pk];
                if (b1 >= 0 && b1 <= 7) {
                    float2 g = Gt[(16 * WQ + b1) * 8 + (ka - amin)];
                    cmac(acc[b1], g, sv);
                }
                if (b2 >= 0 && b2 <= 7) {
                    float2 g = Gt[(16 * WQ + 8 + b2) * 8 + (ka - amin)];
                    cmac(acc[8 + b2], g, sv);
                }
            }
        }
    }
    __syncthreads();
    #pragma unroll
    for (int j = 0; j < 16; j++) {
        const int a = 2 * WQ + (j >> 3), b = j & 7;
        const int po = physw(a * st1 + b * st2);             // compile-time
        S[pb ^ po] = acc[j];
    }
    __syncthreads();
}

template<int M1, int M2>
__device__ __forceinline__ void do_bs(float2* S, const float2* __restrict__ Gt,
                                      int lane, int wq) {
    switch (wq) {
        case 0: bs_gate<M1, M2, 0>(S, Gt, lane); break;
        case 1: bs_gate<M1, M2, 1>(S, Gt, lane); break;
        case 2: bs_gate<M1, M2, 2>(S, Gt, lane); break;
        default: bs_gate<M1, M2, 3>(S, Gt, lane); break;
    }
}

// Single-mode 8x8 dense gate; thread owns 2 private fibers. Ut transposed [k*8+i].
template<int MODE>
__device__ __forceinline__ void one_gate(
    float2* S, const float2* __restrict__ Ut, int t) {
    constexpr int st = 512 >> (3 * MODE);
    constexpr int F0 = (MODE == 0) ? 64 : 512;
    constexpr int F1 = (MODE <= 1) ? 8 : 64;
    constexpr int F2 = (MODE == 3) ? 8 : 1;
    int f0 = t, f1 = t + 256;
    int fb0 = ((f0 >> 6) & 7) * F0 + ((f0 >> 3) & 7) * F1 + (f0 & 7) * F2;
    int fb1 = ((f1 >> 6) & 7) * F0 + ((f1 >> 3) & 7) * F1 + (f1 & 7) * F2;
    int pb0 = physw(fb0), pb1 = physw(fb1);
    float2 a0[8], a1[8];
    #pragma unroll
    for (int i = 0; i < 8; i++) { a0[i] = make_float2(0.f, 0.f); a1[i] = make_float2(0.f, 0.f); }
    #pragma unroll
    for (int k = 0; k < 8; k++) {
        const int pk = physw(k * st);
        float2 s0 = S[pb0 ^ pk];
        float2 s1 = S[pb1 ^ pk];
        const float2* __restrict__ gk = Ut + k * 8;
        #pragma unroll
        for (int i = 0; i < 8; i++) { cmac(a0[i], gk[i], s0); cmac(a1[i], gk[i], s1); }
    }
    #pragma unroll
    for (int i = 0; i < 8; i++) {
        const int pi = physw(i * st);
        S[pb0 ^ pi] = a0[i];
        S[pb1 ^ pi] = a1[i];
    }
    __syncthreads();
}

__global__ __launch_bounds__(256, 4) void sim_kernel(
    const float* __restrict__ coh, const float2* __restrict__ sqm,
    const float2* __restrict__ dpm, const float2* __restrict__ bsG,
    float* __restrict__ out) {
    __shared__ float2 S[AMPS];
    __shared__ float ch[32];
    __shared__ float red[16];
    int b = blockIdx.x;
    int t = threadIdx.x;
    int lane = t & 63;
    int wq = __builtin_amdgcn_readfirstlane(t >> 6);

    if (t < 32) ch[t] = coh[b * 32 + t];
    __syncthreads();
    for (int e = t; e < AMPS; e += 256) {
        float v = ch[e >> 9] * ch[8 + ((e >> 6) & 7)] * ch[16 + ((e >> 3) & 7)] * ch[24 + (e & 7)];
        S[physw(e)] = make_float2(v, 0.f);
    }
    __syncthreads();

    #pragma unroll 1
    for (int l = 0; l < NL; l++) {
        #pragma unroll 1
        for (int h = 0; h < 2; h++) {
            const float2* g = bsG + (size_t)(l * 12 + h * 6) * 512;
            do_bs<0, 1>(S, g + 0 * 512, lane, wq);
            do_bs<0, 2>(S, g + 1 * 512, lane, wq);
            do_bs<0, 3>(S, g + 2 * 512, lane, wq);
            do_bs<1, 2>(S, g + 3 * 512, lane, wq);
            do_bs<1, 3>(S, g + 4 * 512, lane, wq);
            do_bs<2, 3>(S, g + 5 * 512, lane, wq);
            const float2* u = ((h == 0) ? sqm : dpm) + (size_t)(l * 4) * 64;
            one_gate<0>(S, u + 0 * 64, t);
            one_gate<1>(S, u + 1 * 64, t);
            one_gate<2>(S, u + 2 * 64, t);
            one_gate<3>(S, u + 3 * 64, t);
        }
    }

    // <n_w> per mode: iterate logical index, read physical slot.
    float ev0 = 0.f, ev1 = 0.f, ev2 = 0.f, ev3 = 0.f;
    for (int e = t; e < AMPS; e += 256) {
        float2 s = S[physw(e)];
        float pr = s.x * s.x + s.y * s.y;
        ev0 += pr * (float)(e >> 9);
        ev1 += pr * (float)((e >> 6) & 7);
        ev2 += pr * (float)((e >> 3) & 7);
        ev3 += pr * (float)(e & 7);
    }
    #pragma unroll
    for (int off = 32; off > 0; off >>= 1) {
        ev0 += __shfl_down(ev0, off);
        ev1 += __shfl_down(ev1, off);
        ev2 += __shfl_down(ev2, off);
        ev3 += __shfl_down(ev3, off);
    }
    __syncthreads();
    if (lane == 0) {
        red[wq * 4 + 0] = ev0;
        red[wq * 4 + 1] = ev1;
        red[wq * 4 + 2] = ev2;
        red[wq * 4 + 3] = ev3;
    }
    __syncthreads();
    if (t < 4) out[b * 4 + t] = red[t] + red[4 + t] + red[8 + t] + red[12 + t];
}

extern "C" void kernel_launch(void* const* d_in, const int* in_sizes, int n_in,
                              void* d_out, int out_size, void* d_ws, size_t ws_size,
                              hipStream_t stream) {
    const float* x    = (const float*)d_in[0];
    const float* th1  = (const float*)d_in[1];
    const float* ph1  = (const float*)d_in[2];
    const float* th2  = (const float*)d_in[3];
    const float* ph2  = (const float*)d_in[4];
    const float* dpr  = (const float*)d_in[5];
    const float* dpph = (const float*)d_in[6];
    const float* sqr  = (const float*)d_in[7];
    const float* sqph = (const float*)d_in[8];
    const float* kerr = (const float*)d_in[9];
    float* out = (float*)d_out;

    int Bn = in_sizes[0] / NM;

    char* ws = (char*)d_ws;
    float*  coh = (float*)ws;                          // Bn*32 floats
    size_t coh_bytes = (size_t)Bn * 32 * sizeof(float);
    float2* sqm = (float2*)(ws + coh_bytes);           // 16*64 float2
    float2* dpm = (float2*)(ws + coh_bytes + 16 * 64 * sizeof(float2));
    float2* bsG = (float2*)(ws + coh_bytes + 32 * 64 * sizeof(float2)); // 48*512 float2

    int total = Bn * NM;
    coh_kernel<<<(total + 255) / 256, 256, 0, stream>>>(x, coh, total);
    expm8_kernel<<<32, 64, 0, stream>>>(sqr, sqph, dpr, dpph, kerr, sqm, dpm);
    expm64_kernel<<<48, 256, 0, stream>>>(th1, ph1, th2, ph2, bsG);
    sim_kernel<<<Bn, 256, 0, stream>>>(coh, sqm, dpm, bsG, out);
}